// Round 11
// baseline (667.488 us; speedup 1.0000x reference)
//
#include <hip/hip_runtime.h>
#include <hip/hip_bf16.h>
#include <stdint.h>

#define B_ 2
#define T_ 2048
#define C_ 1024
#define H_ 16
#define D_ 64
#define NBLK 768

typedef __attribute__((ext_vector_type(8))) short short8;
typedef __attribute__((ext_vector_type(4))) float floatx4;

__device__ __forceinline__ float bf2f(uint16_t b) {
    return __uint_as_float(((uint32_t)b) << 16);
}
__device__ __forceinline__ uint16_t f2b(float f) {
    __hip_bfloat16 h = __float2bfloat16(f);  // RNE
    return *(uint16_t*)&h;
}
__device__ __forceinline__ float exp2v(float x) {
    float r;
    asm("v_exp_f32 %0, %1" : "=v"(r) : "v"(x));
    return r;
}
__device__ __forceinline__ uint32_t cvtpk(float lo, float hi) {
    uint32_t r;
    asm("v_cvt_pk_bf16_f32 %0, %1, %2" : "=v"(r) : "v"(lo), "v"(hi));
    return r;
}
__device__ __forceinline__ void glds16(const uint16_t* g, uint16_t* l) {
    __builtin_amdgcn_global_load_lds(
        (const __attribute__((address_space(1))) uint32_t*)g,
        (__attribute__((address_space(3))) uint32_t*)l, 16, 0, 0);
}

// ---- device-wide barrier: monotonic counter per phase ----------------------
// __syncthreads() drains vmcnt/lgkmcnt for ALL threads (compiler semantics);
// thread0's __threadfence (agent fence -> L2 writeback) + acquire atomic load
// (cache invalidate) give cross-XCD visibility. Grid = 768 = exactly 3
// blocks/CU (48KB smem, launch_bounds(256,3)) -> all blocks co-resident.
__device__ __forceinline__ void gbar(uint32_t* c) {
    __syncthreads();
    if (threadIdx.x == 0) {
        __threadfence();
        __hip_atomic_fetch_add(c, 1u, __ATOMIC_ACQ_REL, __HIP_MEMORY_SCOPE_AGENT);
        while (__hip_atomic_load(c, __ATOMIC_ACQUIRE, __HIP_MEMORY_SCOPE_AGENT) <
               (uint32_t)NBLK)
            __builtin_amdgcn_s_sleep(2);
        __threadfence();
    }
    __syncthreads();
}

// ------- GEMM phase: C[M,N] = A[M,K] @ Bt[N,K]^T ; bf16 in, fp32 acc -------
// r10 gemm_bt body verbatim; blockIdx/gridDim -> (wgid, nwg); LDS via smem.
template <bool OUT_F32, int BN>
__device__ void gemm_phase(const uint16_t* __restrict__ A,
                           const uint16_t* __restrict__ Bt,
                           void* __restrict__ Cv, int N, int K,
                           int wgid, int nwg, char* smem) {
    constexpr int NJ = BN / 32;
    constexpr int BUFB = BN * 32;
    uint16_t (*As)[128][32] = (uint16_t(*)[128][32])smem;
    uint16_t (*Bs)[BN][32]  = (uint16_t(*)[BN][32])(smem + 24576);
    int tid = threadIdx.x;
    int w = tid >> 6, lane = tid & 63;
    int quad = lane >> 4, l16 = lane & 15;
    int wr = (w >> 1) * 64, wc = (w & 1) * (BN / 2);

    int wg = (wgid & 7) * (nwg >> 3) + (wgid >> 3);
    int nby = N / BN;
    int row0 = (wg / nby) * 128;
    int col0 = (wg % nby) * BN;

    int sr = w * 32 + (lane >> 2);
    int gscA = ((lane & 3) ^ ((lane >> 2) & 3)) * 8;
    uint16_t* lA0 = &As[0][sr][(lane & 3) * 8];
    const uint16_t* gA = A + (size_t)(row0 + sr) * K + gscA;
    int srB = (BN == 128) ? sr : (tid >> 2);
    int gscB = ((lane & 3) ^ (srB & 3)) * 8;
    uint16_t* lB0 = &Bs[0][srB][(lane & 3) * 8];
    const uint16_t* gB = Bt + (size_t)(col0 + srB) * K + gscB;

    floatx4 acc[4][NJ];
    #pragma unroll
    for (int i = 0; i < 4; i++)
        #pragma unroll
        for (int j = 0; j < NJ; j++)
            acc[i][j] = (floatx4){0.f, 0.f, 0.f, 0.f};

#define STAGE3_(bs_, t_)                                                    \
    {                                                                       \
        const uint16_t* ga_ = gA + (size_t)(t_) * 32;                       \
        const uint16_t* gb_ = gB + (size_t)(t_) * 32;                       \
        uint16_t* la_ = lA0 + (bs_) * 4096;                                 \
        uint16_t* lb_ = lB0 + (bs_) * BUFB;                                 \
        glds16(ga_, la_);                                                   \
        glds16(ga_ + 16 * K, la_ + 512);                                    \
        glds16(gb_, lb_);                                                   \
        if constexpr (BN == 128) glds16(gb_ + 16 * K, lb_ + 512);           \
    }

    int NT = K >> 5;                 // K=1024 -> 32 tiles
    STAGE3_(0, 0);
    STAGE3_(1, 1);
    if constexpr (BN == 128)
        asm volatile("s_waitcnt vmcnt(4)" ::: "memory");   // tile 0 resident
    else
        asm volatile("s_waitcnt vmcnt(3)" ::: "memory");
    __builtin_amdgcn_s_barrier();

    const uint16_t* Ab = &As[0][0][0];
    const uint16_t* Bb = &Bs[0][0][0];
    int s = (quad ^ (l16 & 3)) * 8;  // swizzled read slot (loop-invariant)
    int bc = 0, bs = 2;
    for (int t = 0; t < NT; ++t) {
        if (t + 2 < NT) STAGE3_(bs, t + 2);
        const uint16_t* Ac = Ab + bc * 4096;
        const uint16_t* Bc = Bb + bc * BUFB;
        short8 af[4], bfr[NJ];
        #pragma unroll
        for (int i = 0; i < 4; i++)
            af[i] = *(const short8*)&Ac[(wr + i * 16 + l16) * 32 + s];
        #pragma unroll
        for (int j = 0; j < NJ; j++)
            bfr[j] = *(const short8*)&Bc[(wc + j * 16 + l16) * 32 + s];
        #pragma unroll
        for (int i = 0; i < 4; i++)
            #pragma unroll
            for (int j = 0; j < NJ; j++)
                acc[i][j] = __builtin_amdgcn_mfma_f32_16x16x32_bf16(
                    af[i], bfr[j], acc[i][j], 0, 0, 0);
        if (t + 2 < NT) {
            if constexpr (BN == 128)
                asm volatile("s_waitcnt vmcnt(4)" ::: "memory");  // t+1 ready
            else
                asm volatile("s_waitcnt vmcnt(3)" ::: "memory");
        } else {
            asm volatile("s_waitcnt vmcnt(0)" ::: "memory");      // tail drain
        }
        __builtin_amdgcn_s_barrier();
        bc = (bc == 2) ? 0 : bc + 1;
        bs = (bs == 2) ? 0 : bs + 1;
    }
#undef STAGE3_

    #pragma unroll
    for (int i = 0; i < 4; i++) {
        #pragma unroll
        for (int j = 0; j < NJ; j++) {
            int rbase = row0 + wr + i * 16 + quad * 4;
            int cg = col0 + wc + j * 16 + l16;
            #pragma unroll
            for (int r = 0; r < 4; r++) {
                if (OUT_F32)
                    ((float*)Cv)[(size_t)(rbase + r) * N + cg] = acc[i][j][r];
                else
                    ((uint16_t*)Cv)[(size_t)(rbase + r) * N + cg] = f2b(acc[i][j][r]);
            }
        }
    }
}

// ---------------- attn phase (r10 attn_mfma body, id as parameter) ---------
__device__ void attn_phase(const uint16_t* __restrict__ qkv,
                           const float* __restrict__ sink,
                           uint16_t* __restrict__ y, int id, char* smem) {
    uint16_t (*Ks)[64][72] = (uint16_t(*)[64][72])smem;            // 18432 B
    uint16_t (*Vt)[64][72] = (uint16_t(*)[64][72])(smem + 18432);  // 18432 B
    uint16_t (*Pl)[16][72] = (uint16_t(*)[16][72])(smem + 36864);  //  9216 B

    int tid = threadIdx.x;
    int w = tid >> 6, lane = tid & 63;
    int quad = lane >> 4, l16 = lane & 15;

    int strip = 31 - (id >> 5);
    int bh = id & 31;
    int b = bh >> 4, h = bh & 15;
    int q0 = strip * 64 + w * 16;
    int ktiles = strip + 1;

    const uint16_t* qkv_b = qkv + (size_t)b * T_ * 3072;

    const float QSC = 0.125f * 1.44269504f;
    short8 qf[2];
    {
        int qrow = q0 + l16;
        #pragma unroll
        for (int kd = 0; kd < 2; kd++) {
            uint4 raw = *(const uint4*)(qkv_b + (size_t)qrow * 3072 + h * 64 +
                                        kd * 32 + quad * 8);
            const uint16_t* rp = (const uint16_t*)&raw;
            short8 f;
            #pragma unroll
            for (int j = 0; j < 8; j++)
                f[j] = (short)f2b(bf2f(rp[j]) * QSC);
            qf[kd] = f;
        }
    }

    float m_s = sink[h] * 1.44269504f;
    float l_s = 1.0f;
    floatx4 acc_o[4];
    #pragma unroll
    for (int dt = 0; dt < 4; dt++)
        acc_o[dt] = (floatx4){0.f, 0.f, 0.f, 0.f};

    int t2 = tid >> 3;
    int dg = tid & 7;
    const uint16_t* kgp = qkv_b + 1024 + h * 64 + (size_t)(2 * t2) * 3072 + dg * 8;
    const uint16_t* vgp = kgp + 1024;
    int vcw = 2 * (t2 ^ (4 * dg));

    uint4 kr0 = *(const uint4*)(kgp);
    uint4 kr1 = *(const uint4*)(kgp + 3072);
    uint4 vr0 = *(const uint4*)(vgp);
    uint4 vr1 = *(const uint4*)(vgp + 3072);
    {
        *(uint4*)&Ks[0][2 * t2][dg * 8] = kr0;
        *(uint4*)&Ks[0][2 * t2 + 1][dg * 8] = kr1;
        const uint16_t* a0 = (const uint16_t*)&vr0;
        const uint16_t* a1 = (const uint16_t*)&vr1;
        #pragma unroll
        for (int j = 0; j < 8; j++)
            *(uint32_t*)&Vt[0][dg * 8 + j][vcw] =
                (uint32_t)a0[j] | ((uint32_t)a1[j] << 16);
    }
    if (ktiles > 1) {
        kr0 = *(const uint4*)(kgp + 64 * 3072);
        kr1 = *(const uint4*)(kgp + 64 * 3072 + 3072);
        vr0 = *(const uint4*)(vgp + 64 * 3072);
        vr1 = *(const uint4*)(vgp + 64 * 3072 + 3072);
    }
    __syncthreads();

    for (int kt = 0; kt < ktiles; kt++) {
        int cur = kt & 1;
        if (kt + 1 < ktiles) {
            *(uint4*)&Ks[cur ^ 1][2 * t2][dg * 8] = kr0;
            *(uint4*)&Ks[cur ^ 1][2 * t2 + 1][dg * 8] = kr1;
            const uint16_t* a0 = (const uint16_t*)&vr0;
            const uint16_t* a1 = (const uint16_t*)&vr1;
            #pragma unroll
            for (int j = 0; j < 8; j++)
                *(uint32_t*)&Vt[cur ^ 1][dg * 8 + j][vcw] =
                    (uint32_t)a0[j] | ((uint32_t)a1[j] << 16);
        }
        if (kt + 2 < ktiles) {
            size_t off = (size_t)(kt + 2) * 64 * 3072;
            kr0 = *(const uint4*)(kgp + off);
            kr1 = *(const uint4*)(kgp + off + 3072);
            vr0 = *(const uint4*)(vgp + off);
            vr1 = *(const uint4*)(vgp + off + 3072);
        }
        short8 kf[4][2];
        #pragma unroll
        for (int rt = 0; rt < 4; rt++) {
            kf[rt][0] = *(const short8*)&Ks[cur][rt * 16 + l16][quad * 8];
            kf[rt][1] = *(const short8*)&Ks[cur][rt * 16 + l16][32 + quad * 8];
        }
        short8 vf[2][4];
        #pragma unroll
        for (int kb = 0; kb < 2; kb++)
            #pragma unroll
            for (int dt = 0; dt < 4; dt++) {
                int d = dt * 16 + l16;
                int col = 2 * (((kb * 16) + quad * 4) ^ (4 * (d >> 3)));
                vf[kb][dt] = *(const short8*)&Vt[cur][d][col];
            }
        floatx4 acc_s[4];
        #pragma unroll
        for (int rt = 0; rt < 4; rt++)
            acc_s[rt] = (floatx4){0.f, 0.f, 0.f, 0.f};
        #pragma unroll
        for (int rt = 0; rt < 4; rt++) {
            acc_s[rt] = __builtin_amdgcn_mfma_f32_16x16x32_bf16(
                kf[rt][0], qf[0], acc_s[rt], 0, 0, 0);
            acc_s[rt] = __builtin_amdgcn_mfma_f32_16x16x32_bf16(
                kf[rt][1], qf[1], acc_s[rt], 0, 0, 0);
        }
        if (kt == strip) {
            int qg = q0 + l16;
            #pragma unroll
            for (int rt = 0; rt < 4; rt++) {
                int kg = kt * 64 + rt * 16 + quad * 4;
                #pragma unroll
                for (int r = 0; r < 4; r++)
                    if (kg + r > qg) acc_s[rt][r] = -1e30f;
            }
        }
        float mx = -1e30f;
        #pragma unroll
        for (int rt = 0; rt < 4; rt++)
            #pragma unroll
            for (int r = 0; r < 4; r++) mx = fmaxf(mx, acc_s[rt][r]);
        mx = fmaxf(mx, __shfl_xor(mx, 16));
        mx = fmaxf(mx, __shfl_xor(mx, 32));
        float mold = m_s;
        if (!__all(mx <= mold + 8.0f)) {
            float mnew = fmaxf(mold, mx);
            float alpha = exp2v(mold - mnew);
            m_s = mnew;
            l_s *= alpha;
            #pragma unroll
            for (int r = 0; r < 4; r++) {
                float ar = __shfl(alpha, (lane & 48) | (quad * 4 + r));
                #pragma unroll
                for (int dt = 0; dt < 4; dt++) acc_o[dt][r] *= ar;
            }
        }
        float mcur = m_s;
        float psum = 0.f;
        #pragma unroll
        for (int rt = 0; rt < 4; rt++) {
            float p0 = exp2v(acc_s[rt][0] - mcur);
            float p1 = exp2v(acc_s[rt][1] - mcur);
            float p2 = exp2v(acc_s[rt][2] - mcur);
            float p3 = exp2v(acc_s[rt][3] - mcur);
            psum += (p0 + p1) + (p2 + p3);
            uint2 pk;
            pk.x = cvtpk(p0, p1);
            pk.y = cvtpk(p2, p3);
            *(uint2*)&Pl[w][l16][rt * 16 + quad * 4] = pk;
        }
        psum += __shfl_xor(psum, 16);
        psum += __shfl_xor(psum, 32);
        l_s += psum;
        #pragma unroll
        for (int kb = 0; kb < 2; kb++) {
            short8 pf = *(const short8*)&Pl[w][l16][kb * 32 + quad * 8];
            #pragma unroll
            for (int dt = 0; dt < 4; dt++)
                acc_o[dt] = __builtin_amdgcn_mfma_f32_16x16x32_bf16(
                    pf, vf[kb][dt], acc_o[dt], 0, 0, 0);
        }
        __syncthreads();
    }

    #pragma unroll
    for (int r = 0; r < 4; r++) {
        float lr = __shfl(l_s, (lane & 48) | (quad * 4 + r));
        float inv = 1.0f / lr;
        int qg = q0 + quad * 4 + r;
        uint16_t* yp = y + (size_t)(b * T_ + qg) * 1024 + h * 64;
        #pragma unroll
        for (int dt = 0; dt < 4; dt++)
            yp[dt * 16 + l16] = f2b(acc_o[dt][r] * inv);
    }
}

// ---------------- fused persistent kernel: prep|qkv|attn|proj --------------
// Grid 768 = 3 blocks/CU exactly (48KB smem): all co-resident -> software
// device barrier valid. P2 static map: worker w<256 -> ids {w, 1023-w}
// (exactly 33 k-tiles each); w>=256 -> id w (<=24 tiles). xc and yb alias
// (xc dead after P1, yb born in P2).
__global__ __launch_bounds__(256, 3)
void fused(const float* __restrict__ x, const float* __restrict__ w_qkv,
           const float* __restrict__ w_proj, const float* __restrict__ sink,
           float* __restrict__ out, uint16_t* __restrict__ wt_qkv,
           uint16_t* __restrict__ wt_proj, uint16_t* __restrict__ xc_yb,
           uint16_t* __restrict__ qkv, uint32_t* __restrict__ bar) {
    __shared__ __align__(16) char smem[49152];
    int tid = threadIdx.x;
    int bid = blockIdx.x;

    // ---- P0: prep (canon x + weight transposes), grid-stride ----
    for (int id = bid; id < 5120; id += NBLK) {
        if (id < 4096) {
            int i = (id * 256 + tid) * 4;
            float4 v = *(const float4*)(x + i);
            xc_yb[i + 0] = f2b(v.x);
            xc_yb[i + 1] = f2b(v.y);
            xc_yb[i + 2] = f2b(v.z);
            xc_yb[i + 3] = f2b(v.w);
        } else {
            uint16_t (*tile)[65] = (uint16_t(*)[65])smem;
            const float* in;
            uint16_t* op;
            int R, W, bx, by;
            if (id < 4864) {
                int tb = id - 4096;
                in = w_qkv; op = wt_qkv; R = 1024; W = 3072;
                bx = tb % 48; by = tb / 48;
            } else {
                int tb = id - 4864;
                in = w_proj; op = wt_proj; R = 1024; W = 1024;
                bx = tb & 15; by = tb >> 4;
            }
            int tx = tid & 63, ty = tid >> 6;
            int c0 = bx * 64, r0 = by * 64;
            __syncthreads();
            #pragma unroll
            for (int i = 0; i < 64; i += 4)
                tile[ty + i][tx] = f2b(in[(size_t)(r0 + ty + i) * W + (c0 + tx)]);
            __syncthreads();
            #pragma unroll
            for (int i = 0; i < 64; i += 4)
                op[(size_t)(c0 + ty + i) * R + (r0 + tx)] = tile[tx][ty + i];
        }
    }
    gbar(bar + 0);

    // ---- P1: QKV GEMM (768 tiles, 1:1) ----
    gemm_phase<false, 128>(xc_yb, wt_qkv, qkv, 3072, 1024, bid, 768, smem);
    gbar(bar + 1);

    // ---- P2: attention (balanced static map) ----
    if (bid < 256) {
        attn_phase(qkv, sink, xc_yb, bid, smem);
        __syncthreads();
        attn_phase(qkv, sink, xc_yb, 1023 - bid, smem);
    } else {
        attn_phase(qkv, sink, xc_yb, bid, smem);
    }
    gbar(bar + 2);

    // ---- P3: proj GEMM (512 tiles) ----
    if (bid < 512)
        gemm_phase<true, 64>(xc_yb, wt_proj, out, 1024, 1024, bid, 512, smem);
}

extern "C" void kernel_launch(void* const* d_in, const int* in_sizes, int n_in,
                              void* d_out, int out_size, void* d_ws, size_t ws_size,
                              hipStream_t stream) {
    const float* x      = (const float*)d_in[0];  // [B,T,C] fp32
    const float* w_qkv  = (const float*)d_in[1];  // [C, 3HD] fp32
    const float* w_proj = (const float*)d_in[2];  // [HD, C] fp32
    const float* sink   = (const float*)d_in[3];  // [H] fp32
    float* out          = (float*)d_out;          // [B,T,C] fp32

    char* ws = (char*)d_ws;
    uint16_t* wt_qkv  = (uint16_t*)ws;                 // [3072,1024] 6.29 MB
    uint16_t* wt_proj = (uint16_t*)(ws + 6291456);     // [1024,1024] 2.10 MB
    uint16_t* xc_yb   = (uint16_t*)(ws + 8388608);     // x_c then yb  8.39 MB
    uint16_t* qkvb    = (uint16_t*)(ws + 16777216);    // [4096,3072] 25.17 MB
    uint32_t* bar     = (uint32_t*)(ws + 41943040);    // 3 barrier counters

    hipMemsetAsync(bar, 0, 64, stream);
    fused<<<dim3(NBLK), 256, 0, stream>>>(x, w_qkv, w_proj, sink, out,
                                          wt_qkv, wt_proj, xc_yb, qkvb, bar);
}

// Round 12
// 177.426 us; speedup vs baseline: 3.7621x; 3.7621x over previous
//
#include <hip/hip_runtime.h>
#include <hip/hip_bf16.h>
#include <stdint.h>

#define B_ 2
#define T_ 2048
#define C_ 1024
#define H_ 16
#define D_ 64

typedef __attribute__((ext_vector_type(8))) short short8;
typedef __attribute__((ext_vector_type(4))) float floatx4;

__device__ __forceinline__ float bf2f(uint16_t b) {
    return __uint_as_float(((uint32_t)b) << 16);
}
__device__ __forceinline__ uint16_t f2b(float f) {
    __hip_bfloat16 h = __float2bfloat16(f);  // RNE
    return *(uint16_t*)&h;
}
__device__ __forceinline__ float exp2v(float x) {
    float r;
    asm("v_exp_f32 %0, %1" : "=v"(r) : "v"(x));
    return r;
}
__device__ __forceinline__ uint32_t cvtpk(float lo, float hi) {
    uint32_t r;
    asm("v_cvt_pk_bf16_f32 %0, %1, %2" : "=v"(r) : "v"(lo), "v"(hi));
    return r;
}
__device__ __forceinline__ void glds16(const uint16_t* g, uint16_t* l) {
    __builtin_amdgcn_global_load_lds(
        (const __attribute__((address_space(1))) uint32_t*)g,
        (__attribute__((address_space(3))) uint32_t*)l, 16, 0, 0);
}

// ---- fused prep: canon x (fp32->bf16) + both weight transposes ------------
__global__ void prep(const float* __restrict__ x, uint16_t* __restrict__ x_c,
                     const float* __restrict__ w_qkv, uint16_t* __restrict__ wt_qkv,
                     const float* __restrict__ w_proj, uint16_t* __restrict__ wt_proj) {
    __shared__ uint16_t tile[64][65];
    int id = blockIdx.x;
    int tid = threadIdx.x;
    if (id < 4096) {
        int i = (id * 256 + tid) * 4;
        float4 v = *(const float4*)(x + i);
        x_c[i + 0] = f2b(v.x);
        x_c[i + 1] = f2b(v.y);
        x_c[i + 2] = f2b(v.z);
        x_c[i + 3] = f2b(v.w);
        return;
    }
    const float* in;
    uint16_t* out;
    int R, W, bx, by;
    if (id < 4864) {
        int tb = id - 4096;
        in = w_qkv; out = wt_qkv; R = 1024; W = 3072;
        bx = tb % 48; by = tb / 48;
    } else {
        int tb = id - 4864;
        in = w_proj; out = wt_proj; R = 1024; W = 1024;
        bx = tb & 15; by = tb >> 4;
    }
    int tx = tid & 63, ty = tid >> 6;
    int c0 = bx * 64, r0 = by * 64;
    #pragma unroll
    for (int i = 0; i < 64; i += 4)
        tile[ty + i][tx] = f2b(in[(size_t)(r0 + ty + i) * W + (c0 + tx)]);
    __syncthreads();
    #pragma unroll
    for (int i = 0; i < 64; i += 4)
        out[(size_t)(c0 + ty + i) * R + (r0 + tx)] = tile[tx][ty + i];
}

// ------- QKV GEMM: 256x192 tile, BK=64, 8 waves, counted-vmcnt pipeline ----
// A triple-buffered (staged 2 tiles ahead), B double-buffered (1 ahead):
// per tile issue B(t+1) then A(t+2); end-of-tile s_waitcnt vmcnt(4) leaves
// exactly A(t+2) in flight (invariant: [A(t+1)x4 old, B(t+1)x3, A(t+2)x4]).
// Never drains mid-loop (m218: counted-vs-drain is T3's whole gain); ONE
// barrier per K-tile. Buffer rotation mod3/mod2 => no stage targets a
// buffer being read (race-free by construction). 8-slot XOR swizzle
// (slot ^ row&7) with pre-swizzled global source keeps ds_read_b128 at the
// bank floor. Grid 16x16=256 blocks = exactly 1/CU (144KB LDS), bijective
// XCD swizzle. T5 setprio around the MFMA run.
__global__ __launch_bounds__(512, 1)
void gemm_qkv(const uint16_t* __restrict__ A, const uint16_t* __restrict__ Bt,
              uint16_t* __restrict__ C, int M, int N, int K) {
    __shared__ uint16_t As[3][256][64];   // 96 KB
    __shared__ uint16_t Bs[2][192][64];   // 48 KB
    int tid = threadIdx.x;
    int w = tid >> 6, lane = tid & 63;
    int quad = lane >> 4, l16 = lane & 15;
    int wm = w >> 2, wn = w & 3;          // wave grid 2(M) x 4(N)

    int wg = (blockIdx.x & 7) * 32 + (blockIdx.x >> 3);   // 256 % 8 == 0
    int row0 = (wg >> 4) * 256;           // A-panel-major
    int col0 = (wg & 15) * 192;

    // staging: per glds a wave covers 8 rows x 64 cols (lane l -> row l>>3,
    // phys 16B-slot l&7; dest = base + lane*16, contiguous). Pre-swizzled
    // source k-slot = (l&7) ^ (row&7) = (l&7) ^ ((l>>3)&7).
    int srA = w * 32 + (lane >> 3);       // + g*8, g=0..3
    int srB = w * 24 + (lane >> 3);       // + g*8, g=0..2
    int gsc = ((lane & 7) ^ ((lane >> 3) & 7)) * 8;
    uint16_t* lA0 = &As[0][srA][(lane & 7) * 8];
    uint16_t* lB0 = &Bs[0][srB][(lane & 7) * 8];
    const uint16_t* gA = A + (size_t)(row0 + srA) * K + gsc;
    const uint16_t* gB = Bt + (size_t)(col0 + srB) * K + gsc;

    floatx4 acc[8][3];
    #pragma unroll
    for (int i = 0; i < 8; i++)
        #pragma unroll
        for (int j = 0; j < 3; j++)
            acc[i][j] = (floatx4){0.f, 0.f, 0.f, 0.f};

#define STAGEA_(b_, t_)                                                     \
    {                                                                       \
        const uint16_t* g_ = gA + (size_t)(t_) * 64;                        \
        uint16_t* l_ = lA0 + (b_) * (256 * 64);                             \
        _Pragma("unroll") for (int g = 0; g < 4; g++)                       \
            glds16(g_ + (size_t)g * 8 * K, l_ + g * 8 * 64);                \
    }
#define STAGEB_(b_, t_)                                                     \
    {                                                                       \
        const uint16_t* g_ = gB + (size_t)(t_) * 64;                        \
        uint16_t* l_ = lB0 + (b_) * (192 * 64);                             \
        _Pragma("unroll") for (int g = 0; g < 3; g++)                       \
            glds16(g_ + (size_t)g * 8 * K, l_ + g * 8 * 64);                \
    }

    int NT = K >> 6;                      // K=1024 -> 16 tiles
    STAGEA_(0, 0);
    STAGEB_(0, 0);
    STAGEA_(1, 1);
    asm volatile("s_waitcnt vmcnt(4)" ::: "memory");   // tile0 resident
    __builtin_amdgcn_s_barrier();

    int sA = (l16 & 7);                   // row&7 for frag reads
    for (int t = 0; t < NT; ++t) {
        int bufA = t % 3, bufB = t & 1;
        if (t + 1 < NT) STAGEB_(bufB ^ 1, t + 1);
        if (t + 2 < NT) STAGEA_((t + 2) % 3, t + 2);
        // B-frags once per tile (3 j x 2 kk)
        short8 bfr[3][2];
        #pragma unroll
        for (int j = 0; j < 3; j++)
            #pragma unroll
            for (int kk = 0; kk < 2; kk++)
                bfr[j][kk] = *(const short8*)&Bs[bufB][wn * 48 + j * 16 + l16]
                                               [((kk * 4 + quad) ^ sA) * 8];
        __builtin_amdgcn_s_setprio(1);
        #pragma unroll
        for (int i = 0; i < 8; i++) {
            short8 af0 = *(const short8*)&As[bufA][wm * 128 + i * 16 + l16]
                                            [((0 + quad) ^ sA) * 8];
            short8 af1 = *(const short8*)&As[bufA][wm * 128 + i * 16 + l16]
                                            [((4 + quad) ^ sA) * 8];
            #pragma unroll
            for (int j = 0; j < 3; j++) {
                acc[i][j] = __builtin_amdgcn_mfma_f32_16x16x32_bf16(
                    af0, bfr[j][0], acc[i][j], 0, 0, 0);
                acc[i][j] = __builtin_amdgcn_mfma_f32_16x16x32_bf16(
                    af1, bfr[j][1], acc[i][j], 0, 0, 0);
            }
        }
        __builtin_amdgcn_s_setprio(0);
        if (t + 2 < NT) {
            asm volatile("s_waitcnt vmcnt(4)" ::: "memory");  // A(t+2) stays
        } else if (t + 1 < NT) {
            asm volatile("s_waitcnt vmcnt(0)" ::: "memory");  // tail drain
        }
        __builtin_amdgcn_s_barrier();
    }
#undef STAGEA_
#undef STAGEB_

    #pragma unroll
    for (int i = 0; i < 8; i++) {
        #pragma unroll
        for (int j = 0; j < 3; j++) {
            int rbase = row0 + wm * 128 + i * 16 + quad * 4;
            int cg = col0 + wn * 48 + j * 16 + l16;
            #pragma unroll
            for (int r = 0; r < 4; r++)
                C[(size_t)(rbase + r) * N + cg] = f2b(acc[i][j][r]);
        }
    }
}

// ------- proj GEMM (r10 kernel, BN=64): counted-vmcnt BK=32, 3 buffers ----
template <bool OUT_F32, int BN>
__global__ __launch_bounds__(256, 3)
void gemm_bt(const uint16_t* __restrict__ A, const uint16_t* __restrict__ Bt,
             void* __restrict__ Cv, int M, int N, int K) {
    constexpr int NJ = BN / 32;
    constexpr int BUFB = BN * 32;
    __shared__ uint16_t As[3][128][32];
    __shared__ uint16_t Bs[3][BN][32];
    int tid = threadIdx.x;
    int w = tid >> 6, lane = tid & 63;
    int quad = lane >> 4, l16 = lane & 15;
    int wr = (w >> 1) * 64, wc = (w & 1) * (BN / 2);

    int nwg = gridDim.x;
    int wg = (blockIdx.x & 7) * (nwg >> 3) + (blockIdx.x >> 3);
    int nby = N / BN;
    int row0 = (wg / nby) * 128;
    int col0 = (wg % nby) * BN;

    int sr = w * 32 + (lane >> 2);
    int gscA = ((lane & 3) ^ ((lane >> 2) & 3)) * 8;
    uint16_t* lA0 = &As[0][sr][(lane & 3) * 8];
    const uint16_t* gA = A + (size_t)(row0 + sr) * K + gscA;
    int srB = (BN == 128) ? sr : (tid >> 2);
    int gscB = ((lane & 3) ^ (srB & 3)) * 8;
    uint16_t* lB0 = &Bs[0][srB][(lane & 3) * 8];
    const uint16_t* gB = Bt + (size_t)(col0 + srB) * K + gscB;

    floatx4 acc[4][NJ];
    #pragma unroll
    for (int i = 0; i < 4; i++)
        #pragma unroll
        for (int j = 0; j < NJ; j++)
            acc[i][j] = (floatx4){0.f, 0.f, 0.f, 0.f};

#define STAGE3_(bs_, t_)                                                    \
    {                                                                       \
        const uint16_t* ga_ = gA + (size_t)(t_) * 32;                       \
        const uint16_t* gb_ = gB + (size_t)(t_) * 32;                       \
        uint16_t* la_ = lA0 + (bs_) * 4096;                                 \
        uint16_t* lb_ = lB0 + (bs_) * BUFB;                                 \
        glds16(ga_, la_);                                                   \
        glds16(ga_ + 16 * K, la_ + 512);                                    \
        glds16(gb_, lb_);                                                   \
        if constexpr (BN == 128) glds16(gb_ + 16 * K, lb_ + 512);           \
    }

    int NT = K >> 5;
    STAGE3_(0, 0);
    STAGE3_(1, 1);
    if constexpr (BN == 128)
        asm volatile("s_waitcnt vmcnt(4)" ::: "memory");
    else
        asm volatile("s_waitcnt vmcnt(3)" ::: "memory");
    __builtin_amdgcn_s_barrier();

    const uint16_t* Ab = &As[0][0][0];
    const uint16_t* Bb = &Bs[0][0][0];
    int s = (quad ^ (l16 & 3)) * 8;
    int bc = 0, bs = 2;
    for (int t = 0; t < NT; ++t) {
        if (t + 2 < NT) STAGE3_(bs, t + 2);
        const uint16_t* Ac = Ab + bc * 4096;
        const uint16_t* Bc = Bb + bc * BUFB;
        short8 af[4], bfr[NJ];
        #pragma unroll
        for (int i = 0; i < 4; i++)
            af[i] = *(const short8*)&Ac[(wr + i * 16 + l16) * 32 + s];
        #pragma unroll
        for (int j = 0; j < NJ; j++)
            bfr[j] = *(const short8*)&Bc[(wc + j * 16 + l16) * 32 + s];
        #pragma unroll
        for (int i = 0; i < 4; i++)
            #pragma unroll
            for (int j = 0; j < NJ; j++)
                acc[i][j] = __builtin_amdgcn_mfma_f32_16x16x32_bf16(
                    af[i], bfr[j], acc[i][j], 0, 0, 0);
        if (t + 2 < NT) {
            if constexpr (BN == 128)
                asm volatile("s_waitcnt vmcnt(4)" ::: "memory");
            else
                asm volatile("s_waitcnt vmcnt(3)" ::: "memory");
        } else {
            asm volatile("s_waitcnt vmcnt(0)" ::: "memory");
        }
        __builtin_amdgcn_s_barrier();
        bc = (bc == 2) ? 0 : bc + 1;
        bs = (bs == 2) ? 0 : bs + 1;
    }
#undef STAGE3_

    #pragma unroll
    for (int i = 0; i < 4; i++) {
        #pragma unroll
        for (int j = 0; j < NJ; j++) {
            int rbase = row0 + wr + i * 16 + quad * 4;
            int cg = col0 + wc + j * 16 + l16;
            #pragma unroll
            for (int r = 0; r < 4; r++) {
                if (OUT_F32)
                    ((float*)Cv)[(size_t)(rbase + r) * N + cg] = acc[i][j][r];
                else
                    ((uint16_t*)Cv)[(size_t)(rbase + r) * N + cg] = f2b(acc[i][j][r]);
            }
        }
    }
}

// ---------------- MFMA flash attention with sink (round-6/10 version) ------
__global__ __launch_bounds__(256, 3)
void attn_mfma(const uint16_t* __restrict__ qkv,
               const float* __restrict__ sink,
               uint16_t* __restrict__ y) {
    __shared__ uint16_t Ks[2][64][72];
    __shared__ uint16_t Vt[2][64][72];
    __shared__ uint16_t Pl[4][16][72];

    int tid = threadIdx.x;
    int w = tid >> 6, lane = tid & 63;
    int quad = lane >> 4, l16 = lane & 15;

    int id = blockIdx.x;
    int strip = 31 - (id >> 5);
    int bh = id & 31;
    int b = bh >> 4, h = bh & 15;
    int q0 = strip * 64 + w * 16;
    int ktiles = strip + 1;

    const uint16_t* qkv_b = qkv + (size_t)b * T_ * 3072;

    const float QSC = 0.125f * 1.44269504f;
    short8 qf[2];
    {
        int qrow = q0 + l16;
        #pragma unroll
        for (int kd = 0; kd < 2; kd++) {
            uint4 raw = *(const uint4*)(qkv_b + (size_t)qrow * 3072 + h * 64 +
                                        kd * 32 + quad * 8);
            const uint16_t* rp = (const uint16_t*)&raw;
            short8 f;
            #pragma unroll
            for (int j = 0; j < 8; j++)
                f[j] = (short)f2b(bf2f(rp[j]) * QSC);
            qf[kd] = f;
        }
    }

    float m_s = sink[h] * 1.44269504f;
    float l_s = 1.0f;
    floatx4 acc_o[4];
    #pragma unroll
    for (int dt = 0; dt < 4; dt++)
        acc_o[dt] = (floatx4){0.f, 0.f, 0.f, 0.f};

    int t2 = tid >> 3;
    int dg = tid & 7;
    const uint16_t* kgp = qkv_b + 1024 + h * 64 + (size_t)(2 * t2) * 3072 + dg * 8;
    const uint16_t* vgp = kgp + 1024;
    int vcw = 2 * (t2 ^ (4 * dg));

    uint4 kr0 = *(const uint4*)(kgp);
    uint4 kr1 = *(const uint4*)(kgp + 3072);
    uint4 vr0 = *(const uint4*)(vgp);
    uint4 vr1 = *(const uint4*)(vgp + 3072);
    {
        *(uint4*)&Ks[0][2 * t2][dg * 8] = kr0;
        *(uint4*)&Ks[0][2 * t2 + 1][dg * 8] = kr1;
        const uint16_t* a0 = (const uint16_t*)&vr0;
        const uint16_t* a1 = (const uint16_t*)&vr1;
        #pragma unroll
        for (int j = 0; j < 8; j++)
            *(uint32_t*)&Vt[0][dg * 8 + j][vcw] =
                (uint32_t)a0[j] | ((uint32_t)a1[j] << 16);
    }
    if (ktiles > 1) {
        kr0 = *(const uint4*)(kgp + 64 * 3072);
        kr1 = *(const uint4*)(kgp + 64 * 3072 + 3072);
        vr0 = *(const uint4*)(vgp + 64 * 3072);
        vr1 = *(const uint4*)(vgp + 64 * 3072 + 3072);
    }
    __syncthreads();

    for (int kt = 0; kt < ktiles; kt++) {
        int cur = kt & 1;
        if (kt + 1 < ktiles) {
            *(uint4*)&Ks[cur ^ 1][2 * t2][dg * 8] = kr0;
            *(uint4*)&Ks[cur ^ 1][2 * t2 + 1][dg * 8] = kr1;
            const uint16_t* a0 = (const uint16_t*)&vr0;
            const uint16_t* a1 = (const uint16_t*)&vr1;
            #pragma unroll
            for (int j = 0; j < 8; j++)
                *(uint32_t*)&Vt[cur ^ 1][dg * 8 + j][vcw] =
                    (uint32_t)a0[j] | ((uint32_t)a1[j] << 16);
        }
        if (kt + 2 < ktiles) {
            size_t off = (size_t)(kt + 2) * 64 * 3072;
            kr0 = *(const uint4*)(kgp + off);
            kr1 = *(const uint4*)(kgp + off + 3072);
            vr0 = *(const uint4*)(vgp + off);
            vr1 = *(const uint4*)(vgp + off + 3072);
        }
        short8 kf[4][2];
        #pragma unroll
        for (int rt = 0; rt < 4; rt++) {
            kf[rt][0] = *(const short8*)&Ks[cur][rt * 16 + l16][quad * 8];
            kf[rt][1] = *(const short8*)&Ks[cur][rt * 16 + l16][32 + quad * 8];
        }
        short8 vf[2][4];
        #pragma unroll
        for (int kb = 0; kb < 2; kb++)
            #pragma unroll
            for (int dt = 0; dt < 4; dt++) {
                int d = dt * 16 + l16;
                int col = 2 * (((kb * 16) + quad * 4) ^ (4 * (d >> 3)));
                vf[kb][dt] = *(const short8*)&Vt[cur][d][col];
            }
        floatx4 acc_s[4];
        #pragma unroll
        for (int rt = 0; rt < 4; rt++)
            acc_s[rt] = (floatx4){0.f, 0.f, 0.f, 0.f};
        #pragma unroll
        for (int rt = 0; rt < 4; rt++) {
            acc_s[rt] = __builtin_amdgcn_mfma_f32_16x16x32_bf16(
                kf[rt][0], qf[0], acc_s[rt], 0, 0, 0);
            acc_s[rt] = __builtin_amdgcn_mfma_f32_16x16x32_bf16(
                kf[rt][1], qf[1], acc_s[rt], 0, 0, 0);
        }
        if (kt == strip) {
            int qg = q0 + l16;
            #pragma unroll
            for (int rt = 0; rt < 4; rt++) {
                int kg = kt * 64 + rt * 16 + quad * 4;
                #pragma unroll
                for (int r = 0; r < 4; r++)
                    if (kg + r > qg) acc_s[rt][r] = -1e30f;
            }
        }
        float mx = -1e30f;
        #pragma unroll
        for (int rt = 0; rt < 4; rt++)
            #pragma unroll
            for (int r = 0; r < 4; r++) mx = fmaxf(mx, acc_s[rt][r]);
        mx = fmaxf(mx, __shfl_xor(mx, 16));
        mx = fmaxf(mx, __shfl_xor(mx, 32));
        float mold = m_s;
        if (!__all(mx <= mold + 8.0f)) {
            float mnew = fmaxf(mold, mx);
            float alpha = exp2v(mold - mnew);
            m_s = mnew;
            l_s *= alpha;
            #pragma unroll
            for (int r = 0; r < 4; r++) {
                float ar = __shfl(alpha, (lane & 48) | (quad * 4 + r));
                #pragma unroll
                for (int dt = 0; dt < 4; dt++) acc_o[dt][r] *= ar;
            }
        }
        float mcur = m_s;
        float psum = 0.f;
        #pragma unroll
        for (int rt = 0; rt < 4; rt++) {
            float p0 = exp2v(acc_s[rt][0] - mcur);
            float p1 = exp2v(acc_s[rt][1] - mcur);
            float p2 = exp2v(acc_s[rt][2] - mcur);
            float p3 = exp2v(acc_s[rt][3] - mcur);
            psum += (p0 + p1) + (p2 + p3);
            uint2 pk;
            pk.x = cvtpk(p0, p1);
            pk.y = cvtpk(p2, p3);
            *(uint2*)&Pl[w][l16][rt * 16 + quad * 4] = pk;
        }
        psum += __shfl_xor(psum, 16);
        psum += __shfl_xor(psum, 32);
        l_s += psum;
        #pragma unroll
        for (int kb = 0; kb < 2; kb++) {
            short8 pf = *(const short8*)&Pl[w][l16][kb * 32 + quad * 8];
            #pragma unroll
            for (int dt = 0; dt < 4; dt++)
                acc_o[dt] = __builtin_amdgcn_mfma_f32_16x16x32_bf16(
                    pf, vf[kb][dt], acc_o[dt], 0, 0, 0);
        }
        __syncthreads();
    }

    #pragma unroll
    for (int r = 0; r < 4; r++) {
        float lr = __shfl(l_s, (lane & 48) | (quad * 4 + r));
        float inv = 1.0f / lr;
        int qg = q0 + quad * 4 + r;
        uint16_t* yp = y + (size_t)(b * T_ + qg) * 1024 + h * 64;
        #pragma unroll
        for (int dt = 0; dt < 4; dt++)
            yp[dt * 16 + l16] = f2b(acc_o[dt][r] * inv);
    }
}

extern "C" void kernel_launch(void* const* d_in, const int* in_sizes, int n_in,
                              void* d_out, int out_size, void* d_ws, size_t ws_size,
                              hipStream_t stream) {
    const float* x      = (const float*)d_in[0];  // [B,T,C] fp32
    const float* w_qkv  = (const float*)d_in[1];  // [C, 3HD] fp32
    const float* w_proj = (const float*)d_in[2];  // [HD, C] fp32
    const float* sink   = (const float*)d_in[3];  // [H] fp32
    float* out          = (float*)d_out;          // [B,T,C] fp32

    char* ws = (char*)d_ws;
    uint16_t* wt_qkv  = (uint16_t*)ws;                       // [3072,1024] 6.29 MB
    uint16_t* wt_proj = (uint16_t*)(ws + 6291456);           // [1024,1024] 2.10 MB
    uint16_t* x_c     = (uint16_t*)(ws + 8388608);           // [4096,1024] 8.39 MB
    uint16_t* qkv     = (uint16_t*)(ws + 16777216);          // [4096,3072] 25.17 MB
    uint16_t* yb      = (uint16_t*)(ws + 41943040);          // [4096,1024] 8.39 MB

    // fused prep: canon + both transposes (64x64 tiles) in ONE dispatch
    prep<<<dim3(5120), 256, 0, stream>>>(x, x_c, w_qkv, wt_qkv, w_proj, wt_proj);

    // QKV: 256x192 tiles, 256 blocks = 1/CU, counted-vmcnt deep pipeline
    gemm_qkv<<<dim3(256), 512, 0, stream>>>(x_c, wt_qkv, qkv, 4096, 3072, 1024);

    // strip-per-block grid: id = (31-strip)*32 + bh (longest first; id%8=bh%8)
    attn_mfma<<<dim3(32 * 32), 256, 0, stream>>>(qkv, sink, yb);

    // proj: 128x64 tiles -> 512 blocks = 2 blocks/CU
    gemm_bt<true, 64><<<dim3(512), 256, 0, stream>>>(
        yb, wt_proj, out, 4096, 1024, 1024);
}